// Round 13
// baseline (241.183 us; speedup 1.0000x reference)
//
#include <hip/hip_runtime.h>

typedef _Float16 half8  __attribute__((ext_vector_type(8)));
typedef _Float16 half4  __attribute__((ext_vector_type(4)));
typedef __fp16   half2v __attribute__((ext_vector_type(2)));   // cvt_pkrtz return type
typedef float    f32x4  __attribute__((ext_vector_type(4)));
typedef float    f32x2  __attribute__((ext_vector_type(2)));

#define L2E 1.44269504088896340736f
#define MFMA(a, b, c)   __builtin_amdgcn_mfma_f32_16x16x32_f16((a), (b), (c), 0, 0, 0)
#define MFMA16(a, b, c) __builtin_amdgcn_mfma_f32_16x16x16f16((a), (b), (c), 0, 0, 0)

// Row-permuted + pre-scaled weights: D-fragment of gates^T = Wc·h^T lands
// i,f,g,o for (agent=col, j=8q+i) in-lane; activation output is directly the
// next step's B-fragment. slot s: gi=s>>5, hf=(s>>4)&1, q=(s>>2)&3, r=s&3
//   -> orig gate row o = gi*32 + 8q + 4hf + r.
// ws layout (float offsets):
//   0    : Wcs [128][32]  permuted, scaled folded recurrent weights
//   8192 : W00s[128]      permuted, scaled lp0 rank-1 column
//   8320 : W01s[128]      permuted, scaled lp1 rank-1 column
//   8448 : bg2s[128]      permuted, scaled steady-state gate bias
//   8704 : phf [64][4]    per-lane prebuilt f16 pos-head A-fragment (u32 x4)
__global__ void precompute_kernel(const float* __restrict__ W_se,
                                  const float* __restrict__ b_se,
                                  const float* __restrict__ W_ih,
                                  const float* __restrict__ b_ih,
                                  const float* __restrict__ W_hh,
                                  const float* __restrict__ b_hh,
                                  const float* __restrict__ W_hp,
                                  const float* __restrict__ b_hp,
                                  float* __restrict__ ws) {
    int s = threadIdx.x;
    if (s >= 128) return;
    // pos-head fragment table (lanes 0..63)
    if (s < 64) {
        int colp = s & 15, qp = s >> 4;
        unsigned int* dst = (unsigned int*)ws + 8704 + s * 4;
        for (int pp = 0; pp < 4; ++pp) {
            float v0 = (colp < 2) ? W_hp[colp * 32 + 8 * qp + 2 * pp]     : 0.f;
            float v1 = (colp < 2) ? W_hp[colp * 32 + 8 * qp + 2 * pp + 1] : 0.f;
            half2v h2 = __builtin_amdgcn_cvt_pkrtz(v0, v1);
            dst[pp] = __builtin_bit_cast(unsigned int, h2);
        }
    }
    int gi = s >> 5, hf = (s >> 4) & 1, q = (s >> 2) & 3, r = s & 3;
    int o  = gi * 32 + 8 * q + 4 * hf + r;          // original gate row
    float w0 = 0.f, w1 = 0.f, bse = 0.f;
    for (int e = 0; e < 32; ++e) {
        float wi = W_ih[o * 32 + e];
        w0  += W_se[e * 2 + 0] * wi;
        w1  += W_se[e * 2 + 1] * wi;
        bse += b_se[e] * wi;
    }
    // i,f,o rows scaled by -log2e (sigmoid via exp2); g rows by 2*log2e (tanh)
    float sc = (gi == 2) ? 2.0f * L2E : -L2E;
    for (int k = 0; k < 32; ++k) {
        float whh = W_hh[o * 32 + k];
        ws[s * 32 + k] = sc * (whh + W_hp[k] * w0 + W_hp[32 + k] * w1);
    }
    float bg = b_ih[o] + b_hh[o] + bse;
    ws[8192 + s] = sc * w0;
    ws[8320 + s] = sc * w1;
    ws[8448 + s] = sc * (bg + b_hp[0] * w0 + b_hp[1] * w1);
}

// exact hi/lo f16 split of 8 floats
__device__ __forceinline__ void split8(const float* v, half8& hi, half8& lo) {
    #pragma unroll
    for (int p = 0; p < 4; ++p) {
        half2v hp = __builtin_amdgcn_cvt_pkrtz(v[2 * p], v[2 * p + 1]);
        hi[2 * p] = hp.x; hi[2 * p + 1] = hp.y;
        float l0 = v[2 * p]     - (float)hp.x;
        float l1 = v[2 * p + 1] - (float)hp.y;
        half2v lp2 = __builtin_amdgcn_cvt_pkrtz(l0, l1);
        lo[2 * p] = lp2.x; lo[2 * p + 1] = lp2.y;
    }
}

// Single tile per wave, 4 waves/block. Weights + biases in per-block LDS
// (volatile reads -> never persistent registers). K-split 16x16x16 MFMAs so
// act(hf1) (odd accg tiles) overlaps the even tiles' k0 MFMAs.
__global__ __launch_bounds__(256, 4) void lstm_kernel(
        const float* __restrict__ lp,    // last_pos_rel (B,2)
        const float* __restrict__ h0g,   // hidden_state (1,B,32)
        const float* __restrict__ sp,    // start_pos (B,2)
        const float* __restrict__ bhp,   // (2)
        const float* __restrict__ ws,
        const int*   __restrict__ seqp,
        float* __restrict__ out, int Bn) {
    __shared__ f32x4 wh_lds[8][64];      // [t8][lane] f16x8 fragments, 8 KB
    __shared__ f32x4 bias_lds[32];       // [t8*4+q] gate bias, 512 B

    const int tid  = threadIdx.x;
    const int lane = tid & 63;
    const int col  = lane & 15;          // agent within tile
    const int q    = lane >> 4;
    int base = (blockIdx.x * 4 + (tid >> 6)) * 16;
    if (base + 16 > Bn) base = (Bn >= 16) ? (Bn - 16) : 0;   // clamp; no early return (barrier)
    const int T = seqp[0];

    const float* Wcs  = ws;
    const float* W00s = ws + 8192;
    const float* W01s = ws + 8320;
    const float* phb  = ws + 8704;           // pos-head fragment table

    // ---- build shared tables (wave 0) ----
    if (tid < 64) {
        #pragma unroll
        for (int t8 = 0; t8 < 8; ++t8) {
            const float* p = Wcs + (size_t)(t8 * 16 + (tid & 15)) * 32 + 8 * (tid >> 4);
            half8 w;
            #pragma unroll
            for (int pp = 0; pp < 4; ++pp) {
                half2v h2 = __builtin_amdgcn_cvt_pkrtz(p[2 * pp], p[2 * pp + 1]);
                w[2 * pp] = h2.x; w[2 * pp + 1] = h2.y;
            }
            wh_lds[t8][tid] = __builtin_bit_cast(f32x4, w);
        }
    } else if (tid >= 128 && tid < 160) {
        bias_lds[tid - 128] = *(const f32x4*)(ws + 8448 + (tid - 128) * 4);
    }
    __syncthreads();

    // volatile LDS reads: never hoisted into persistent registers
    #define WHT(t8) __builtin_bit_cast(half8, *(volatile const f32x4*)&wh_lds[(t8)][lane])
    #define BIA(t8) (*(volatile const f32x4*)&bias_lds[(t8) * 4 + q])
    #define LO4(w)  __builtin_shufflevector((w), (w), 0, 1, 2, 3)
    #define HI4(w)  __builtin_shufflevector((w), (w), 4, 5, 6, 7)

    // persistent pos-head fragment (4 regs) + bias scalars
    half8 pht = __builtin_bit_cast(half8, *(const f32x4*)(phb + lane * 4));
    const half4 phlo = LO4(pht), phhi = HI4(pht);
    const float pb0 = (q == 0) ? bhp[0] : 0.f;
    const float pb1 = (q == 0) ? bhp[1] : 0.f;

    // ---- step 0 via correction identity:
    //      gates_0 = wh*h0 + bg2 + W0 (x) (lp - (Whp*h0 + bhp)) ----
    f32x4 accg[8];
    {
        half8 b0h, b0l;                  // h0 fragment, exact hi/lo
        {
            float v[8];
            const float* p = h0g + (size_t)(base + col) * 32 + 8 * q;
            #pragma unroll
            for (int i = 0; i < 8; ++i) v[i] = p[i];
            split8(v, b0h, b0l);
        }
        f32x4 ap;
        ap[0] = pb0; ap[1] = pb1; ap[2] = 0.f; ap[3] = 0.f;
        ap = MFMA(pht, b0h, ap);
        ap = MFMA(pht, b0l, ap);
        half8 dh;                        // delta = lp - p~  (k=0,1 live on q==0)
        #pragma unroll
        for (int i = 0; i < 8; ++i) dh[i] = (_Float16)0.f;
        if (q == 0) {
            float d0 = lp[(size_t)(base + col) * 2 + 0] - ap[0];
            float d1 = lp[(size_t)(base + col) * 2 + 1] - ap[1];
            half2v x = __builtin_amdgcn_cvt_pkrtz(d0, d1);
            dh[0] = x.x; dh[1] = x.y;
        }
        #pragma unroll
        for (int t8 = 0; t8 < 8; ++t8) {
            f32x4 a = BIA(t8);
            half8 w = WHT(t8);
            a = MFMA(w, b0h, a);
            a = MFMA(w, b0l, a);
            half8 ch;                    // rank-2 correction A-fragment
            #pragma unroll
            for (int i = 0; i < 8; ++i) ch[i] = (_Float16)0.f;
            if (q == 0) {
                half2v y = __builtin_amdgcn_cvt_pkrtz(W00s[t8 * 16 + col],
                                                      W01s[t8 * 16 + col]);
                ch[0] = y.x; ch[1] = y.y;
            }
            a = MFMA(ch, dh, a);
            accg[t8] = a;
        }
    }

    // per-lane recurrent state: agent=col, hidden j = 8q+i
    f32x2 c2[4];
    #pragma unroll
    for (int i = 0; i < 4; ++i) c2[i] = (f32x2)0.f;
    float run0 = 0.f, run1 = 0.f;
    if (q == 0) {
        run0 = sp[(size_t)(base + col) * 2 + 0];
        run1 = sp[(size_t)(base + col) * 2 + 1];
    }

    half4 bhlo, bhhi;                    // h as f16 B-fragment halves

    // activation packet: 2 elements -> f16 into bh half (idx local 0/1)
    auto act2 = [&](f32x4* accg_, half4& bhh, int hf, int rp) {
        const int idx = 2 * hf + rp;
        f32x2 gI, gF, gG, gO;
        gI.x = accg_[0 + hf][2 * rp]; gI.y = accg_[0 + hf][2 * rp + 1];
        gF.x = accg_[2 + hf][2 * rp]; gF.y = accg_[2 + hf][2 * rp + 1];
        gG.x = accg_[4 + hf][2 * rp]; gG.y = accg_[4 + hf][2 * rp + 1];
        gO.x = accg_[6 + hf][2 * rp]; gO.y = accg_[6 + hf][2 * rp + 1];
        f32x2 ei, ef, eg, eo;
        ei.x = __builtin_amdgcn_exp2f(gI.x); ei.y = __builtin_amdgcn_exp2f(gI.y);
        ef.x = __builtin_amdgcn_exp2f(gF.x); ef.y = __builtin_amdgcn_exp2f(gF.y);
        eg.x = __builtin_amdgcn_exp2f(gG.x); eg.y = __builtin_amdgcn_exp2f(gG.y);
        eo.x = __builtin_amdgcn_exp2f(gO.x); eo.y = __builtin_amdgcn_exp2f(gO.y);
        f32x2 Df = ef + 1.f;
        f32x2 P  = (ei + 1.f) * (eg + 1.f);
        f32x2 PD = P * Df;
        f32x2 R;
        R.x = __builtin_amdgcn_rcpf(PD.x); R.y = __builtin_amdgcn_rcpf(PD.y);
        f32x2 cn = ((eg - 1.f) * Df + c2[idx] * P) * R;
        c2[idx] = cn;
        f32x2 arg = cn * (2.f * L2E);
        f32x2 ec;
        ec.x = __builtin_amdgcn_exp2f(arg.x); ec.y = __builtin_amdgcn_exp2f(arg.y);
        f32x2 DDo = (ec + 1.f) * (eo + 1.f);
        f32x2 Rs;
        Rs.x = __builtin_amdgcn_rcpf(DDo.x); Rs.y = __builtin_amdgcn_rcpf(DDo.y);
        f32x2 h2 = (ec - 1.f) * Rs;
        half2v hp = __builtin_amdgcn_cvt_pkrtz(h2.x, h2.y);
        bhh[2 * rp] = hp.x; bhh[2 * rp + 1] = hp.y;
    };

    #pragma unroll 1
    for (int n = 0; n < T; ++n) {
        // ---- act hf0 (reads EVEN accg tiles) -> bh_lo (j = 8q+0..3) ----
        act2(accg, bhlo, 0, 0);
        act2(accg, bhlo, 0, 1);

        // ---- k0 MFMAs for EVEN tiles (consumed), overlap with act hf1 ----
        half4 whiE[4];
        #pragma unroll
        for (int e = 0; e < 4; ++e) {
            const int t8 = 2 * e;
            half8 w = WHT(t8);
            whiE[e] = HI4(w);
            accg[t8] = MFMA16(LO4(w), bhlo, BIA(t8));
        }

        // ---- act hf1 (reads ODD accg tiles) -> bh_hi (j = 8q+4..7) ----
        act2(accg, bhhi, 1, 0);
        act2(accg, bhhi, 1, 1);

        // ---- pos head (k-split) ----
        f32x4 ap;
        ap[0] = pb0; ap[1] = pb1; ap[2] = 0.f; ap[3] = 0.f;
        ap = MFMA16(phlo, bhlo, ap);
        ap = MFMA16(phhi, bhhi, ap);

        // ---- odd tiles k0+k1; even tiles k1 ----
        #pragma unroll
        for (int e = 0; e < 4; ++e) {
            const int t8 = 2 * e + 1;
            half8 w = WHT(t8);
            f32x4 a = MFMA16(LO4(w), bhlo, BIA(t8));
            accg[t8] = MFMA16(HI4(w), bhhi, a);
        }
        #pragma unroll
        for (int e = 0; e < 4; ++e)
            accg[2 * e] = MFMA16(whiE[e], bhhi, accg[2 * e]);

        // ---- cumsum + coalesced float2 store (lanes 0..15) ----
        if (q == 0) {
            run0 += ap[0]; run1 += ap[1];
            float2 w2; w2.x = run0; w2.y = run1;
            *(float2*)(out + 2 * ((size_t)n * Bn + base + col)) = w2;
        }
    }

    // ---- final hidden state from the f16 fragments (error ~2.4e-4) ----
    {
        float* p = out + (size_t)T * Bn * 2 + (size_t)(base + col) * 32 + 8 * q;
        float4 v0, v1;
        v0.x = (float)bhlo[0]; v0.y = (float)bhlo[1]; v0.z = (float)bhlo[2]; v0.w = (float)bhlo[3];
        v1.x = (float)bhhi[0]; v1.y = (float)bhhi[1]; v1.z = (float)bhhi[2]; v1.w = (float)bhhi[3];
        *(float4*)(p)     = v0;
        *(float4*)(p + 4) = v1;
    }
    #undef WHT
    #undef BIA
    #undef LO4
    #undef HI4
}

extern "C" void kernel_launch(void* const* d_in, const int* in_sizes, int n_in,
                              void* d_out, int out_size, void* d_ws, size_t ws_size,
                              hipStream_t stream) {
    const float* last_pos_rel = (const float*)d_in[0];
    const float* hidden_state = (const float*)d_in[1];
    const float* start_pos    = (const float*)d_in[2];
    const float* W_se         = (const float*)d_in[3];
    const float* b_se         = (const float*)d_in[4];
    const float* W_ih         = (const float*)d_in[5];
    const float* b_ih         = (const float*)d_in[6];
    const float* W_hh         = (const float*)d_in[7];
    const float* b_hh         = (const float*)d_in[8];
    const float* W_hp         = (const float*)d_in[9];
    const float* b_hp         = (const float*)d_in[10];
    const int*   seq_len      = (const int*)d_in[11];

    float* out = (float*)d_out;
    float* ws  = (float*)d_ws;

    const int Bn = in_sizes[0] / 2;

    hipLaunchKernelGGL(precompute_kernel, dim3(1), dim3(128), 0, stream,
                       W_se, b_se, W_ih, b_ih, W_hh, b_hh, W_hp, b_hp, ws);

    const int ntiles = (Bn + 15) / 16;
    const int nblk   = (ntiles + 3) / 4;
    hipLaunchKernelGGL(lstm_kernel, dim3(nblk), dim3(256), 0, stream,
                       last_pos_rel, hidden_state, start_pos, b_hp,
                       ws, seq_len, out, Bn);
}

// Round 14
// 208.097 us; speedup vs baseline: 1.1590x; 1.1590x over previous
//
#include <hip/hip_runtime.h>

typedef _Float16 half8  __attribute__((ext_vector_type(8)));
typedef __fp16   half2v __attribute__((ext_vector_type(2)));   // cvt_pkrtz return type
typedef float    f32x4  __attribute__((ext_vector_type(4)));
typedef float    f32x2  __attribute__((ext_vector_type(2)));

#define L2E 1.44269504088896340736f
#define MFMA(a, b, c) __builtin_amdgcn_mfma_f32_16x16x32_f16((a), (b), (c), 0, 0, 0)

// Row-permuted + pre-scaled weights: D-fragment of gates^T = Wc·h^T lands
// i,f,g,o for (agent=col, j=8q+i) in-lane; activation output is directly the
// next step's B-fragment. slot s: gi=s>>5, hf=(s>>4)&1, q=(s>>2)&3, r=s&3
//   -> orig gate row o = gi*32 + 8q + 4hf + r.
// ws layout (float offsets):
//   0    : Wcs [128][32]  permuted, scaled folded recurrent weights
//   8192 : W00s[128]      permuted, scaled lp0 rank-1 column
//   8320 : W01s[128]      permuted, scaled lp1 rank-1 column
//   8448 : bg2s[128]      permuted, scaled steady-state gate bias
//   8704 : phf [64][4]    per-lane prebuilt f16 pos-head A-fragment (u32 x4)
__global__ void precompute_kernel(const float* __restrict__ W_se,
                                  const float* __restrict__ b_se,
                                  const float* __restrict__ W_ih,
                                  const float* __restrict__ b_ih,
                                  const float* __restrict__ W_hh,
                                  const float* __restrict__ b_hh,
                                  const float* __restrict__ W_hp,
                                  const float* __restrict__ b_hp,
                                  float* __restrict__ ws) {
    int s = threadIdx.x;
    if (s >= 128) return;
    // pos-head fragment table (lanes 0..63)
    if (s < 64) {
        int colp = s & 15, qp = s >> 4;
        unsigned int* dst = (unsigned int*)ws + 8704 + s * 4;
        for (int pp = 0; pp < 4; ++pp) {
            float v0 = (colp < 2) ? W_hp[colp * 32 + 8 * qp + 2 * pp]     : 0.f;
            float v1 = (colp < 2) ? W_hp[colp * 32 + 8 * qp + 2 * pp + 1] : 0.f;
            half2v h2 = __builtin_amdgcn_cvt_pkrtz(v0, v1);
            dst[pp] = __builtin_bit_cast(unsigned int, h2);
        }
    }
    int gi = s >> 5, hf = (s >> 4) & 1, q = (s >> 2) & 3, r = s & 3;
    int o  = gi * 32 + 8 * q + 4 * hf + r;          // original gate row
    float w0 = 0.f, w1 = 0.f, bse = 0.f;
    for (int e = 0; e < 32; ++e) {
        float wi = W_ih[o * 32 + e];
        w0  += W_se[e * 2 + 0] * wi;
        w1  += W_se[e * 2 + 1] * wi;
        bse += b_se[e] * wi;
    }
    // i,f,o rows scaled by -log2e (sigmoid via exp2); g rows by 2*log2e (tanh)
    float sc = (gi == 2) ? 2.0f * L2E : -L2E;
    for (int k = 0; k < 32; ++k) {
        float whh = W_hh[o * 32 + k];
        ws[s * 32 + k] = sc * (whh + W_hp[k] * w0 + W_hp[32 + k] * w1);
    }
    float bg = b_ih[o] + b_hh[o] + bse;
    ws[8192 + s] = sc * w0;
    ws[8320 + s] = sc * w1;
    ws[8448 + s] = sc * (bg + b_hp[0] * w0 + b_hp[1] * w1);
}

// exact hi/lo f16 split of 8 floats
__device__ __forceinline__ void split8(const float* v, half8& hi, half8& lo) {
    #pragma unroll
    for (int p = 0; p < 4; ++p) {
        half2v hp = __builtin_amdgcn_cvt_pkrtz(v[2 * p], v[2 * p + 1]);
        hi[2 * p] = hp.x; hi[2 * p + 1] = hp.y;
        float l0 = v[2 * p]     - (float)hp.x;
        float l1 = v[2 * p + 1] - (float)hp.y;
        half2v lp2 = __builtin_amdgcn_cvt_pkrtz(l0, l1);
        lo[2 * p] = lp2.x; lo[2 * p + 1] = lp2.y;
    }
}

// Single tile per wave, 4 waves/block. Weights + biases in per-block LDS
// (volatile reads -> never persistent registers). Activations batch all gate
// exps per j-half before the rcp combine chains (max in-wave trans ILP).
__global__ __launch_bounds__(256, 4) void lstm_kernel(
        const float* __restrict__ lp,    // last_pos_rel (B,2)
        const float* __restrict__ h0g,   // hidden_state (1,B,32)
        const float* __restrict__ sp,    // start_pos (B,2)
        const float* __restrict__ bhp,   // (2)
        const float* __restrict__ ws,
        const int*   __restrict__ seqp,
        float* __restrict__ out, int Bn) {
    __shared__ f32x4 wh_lds[8][64];      // [t8][lane] f16x8 fragments, 8 KB
    __shared__ f32x4 bias_lds[32];       // [t8*4+q] gate bias, 512 B

    const int tid  = threadIdx.x;
    const int lane = tid & 63;
    const int col  = lane & 15;          // agent within tile
    const int q    = lane >> 4;
    int base = (blockIdx.x * 4 + (tid >> 6)) * 16;
    if (base + 16 > Bn) base = (Bn >= 16) ? (Bn - 16) : 0;   // clamp; no early return (barrier)
    const int T = seqp[0];

    const float* Wcs  = ws;
    const float* W00s = ws + 8192;
    const float* W01s = ws + 8320;
    const float* phb  = ws + 8704;           // pos-head fragment table

    // ---- build shared tables ----
    if (tid < 64) {
        #pragma unroll
        for (int t8 = 0; t8 < 8; ++t8) {
            const float* p = Wcs + (size_t)(t8 * 16 + (tid & 15)) * 32 + 8 * (tid >> 4);
            half8 w;
            #pragma unroll
            for (int pp = 0; pp < 4; ++pp) {
                half2v h2 = __builtin_amdgcn_cvt_pkrtz(p[2 * pp], p[2 * pp + 1]);
                w[2 * pp] = h2.x; w[2 * pp + 1] = h2.y;
            }
            wh_lds[t8][tid] = __builtin_bit_cast(f32x4, w);
        }
    } else if (tid >= 128 && tid < 160) {
        bias_lds[tid - 128] = *(const f32x4*)(ws + 8448 + (tid - 128) * 4);
    }
    __syncthreads();

    // volatile LDS reads: never hoisted into persistent registers
    #define WHT(t8) __builtin_bit_cast(half8, *(volatile const f32x4*)&wh_lds[(t8)][lane])
    #define BIA(t8) (*(volatile const f32x4*)&bias_lds[(t8) * 4 + q])

    // persistent pos-head fragment (4 regs) + bias scalars
    half8 pht = __builtin_bit_cast(half8, *(const f32x4*)(phb + lane * 4));
    const float pb0 = (q == 0) ? bhp[0] : 0.f;
    const float pb1 = (q == 0) ? bhp[1] : 0.f;

    // ---- step 0 via correction identity:
    //      gates_0 = wh*h0 + bg2 + W0 (x) (lp - (Whp*h0 + bhp)) ----
    f32x4 accg[8];
    {
        half8 b0h, b0l;                  // h0 fragment, exact hi/lo
        {
            float v[8];
            const float* p = h0g + (size_t)(base + col) * 32 + 8 * q;
            #pragma unroll
            for (int i = 0; i < 8; ++i) v[i] = p[i];
            split8(v, b0h, b0l);
        }
        f32x4 ap;
        ap[0] = pb0; ap[1] = pb1; ap[2] = 0.f; ap[3] = 0.f;
        ap = MFMA(pht, b0h, ap);
        ap = MFMA(pht, b0l, ap);
        half8 dh;                        // delta = lp - p~  (k=0,1 live on q==0)
        #pragma unroll
        for (int i = 0; i < 8; ++i) dh[i] = (_Float16)0.f;
        if (q == 0) {
            float d0 = lp[(size_t)(base + col) * 2 + 0] - ap[0];
            float d1 = lp[(size_t)(base + col) * 2 + 1] - ap[1];
            half2v x = __builtin_amdgcn_cvt_pkrtz(d0, d1);
            dh[0] = x.x; dh[1] = x.y;
        }
        #pragma unroll
        for (int t8 = 0; t8 < 8; ++t8) {
            f32x4 a = BIA(t8);
            half8 w = WHT(t8);
            a = MFMA(w, b0h, a);
            a = MFMA(w, b0l, a);
            half8 ch;                    // rank-2 correction A-fragment
            #pragma unroll
            for (int i = 0; i < 8; ++i) ch[i] = (_Float16)0.f;
            if (q == 0) {
                half2v y = __builtin_amdgcn_cvt_pkrtz(W00s[t8 * 16 + col],
                                                      W01s[t8 * 16 + col]);
                ch[0] = y.x; ch[1] = y.y;
            }
            a = MFMA(ch, dh, a);
            accg[t8] = a;
        }
    }

    // per-lane recurrent state: agent=col, hidden j = 8q+i
    f32x2 c2[4];
    #pragma unroll
    for (int i = 0; i < 4; ++i) c2[i] = (f32x2)0.f;
    float run0 = 0.f, run1 = 0.f;
    if (q == 0) {
        run0 = sp[(size_t)(base + col) * 2 + 0];
        run1 = sp[(size_t)(base + col) * 2 + 1];
    }

    half8 bh;                            // h as f16 B-fragment (persists to epilogue)

    #pragma unroll 1
    for (int n = 0; n < T; ++n) {
        // ---- activations per j-half: batch ALL gate exps, then combine ----
        #pragma unroll
        for (int hf = 0; hf < 2; ++hf) {
            // phase 1: 16 exp2 (4 gates x f32x4), issued back-to-back
            f32x4 Ei, Ef, Eg, Eo;
            #pragma unroll
            for (int k = 0; k < 4; ++k) Ei[k] = __builtin_amdgcn_exp2f(accg[0 + hf][k]);
            #pragma unroll
            for (int k = 0; k < 4; ++k) Ef[k] = __builtin_amdgcn_exp2f(accg[2 + hf][k]);
            #pragma unroll
            for (int k = 0; k < 4; ++k) Eg[k] = __builtin_amdgcn_exp2f(accg[4 + hf][k]);
            #pragma unroll
            for (int k = 0; k < 4; ++k) Eo[k] = __builtin_amdgcn_exp2f(accg[6 + hf][k]);
            // phase 2: per 2-element packet combine (both rcp chains independent)
            #pragma unroll
            for (int rp = 0; rp < 2; ++rp) {
                const int idx = 2 * hf + rp;
                f32x2 ei, ef, eg, eo;
                ei.x = Ei[2 * rp]; ei.y = Ei[2 * rp + 1];
                ef.x = Ef[2 * rp]; ef.y = Ef[2 * rp + 1];
                eg.x = Eg[2 * rp]; eg.y = Eg[2 * rp + 1];
                eo.x = Eo[2 * rp]; eo.y = Eo[2 * rp + 1];
                f32x2 Df = ef + 1.f;
                f32x2 P  = (ei + 1.f) * (eg + 1.f);
                f32x2 PD = P * Df;
                f32x2 R;
                R.x = __builtin_amdgcn_rcpf(PD.x); R.y = __builtin_amdgcn_rcpf(PD.y);
                f32x2 cn = ((eg - 1.f) * Df + c2[idx] * P) * R;
                c2[idx] = cn;
                f32x2 arg = cn * (2.f * L2E);
                f32x2 ec;
                ec.x = __builtin_amdgcn_exp2f(arg.x); ec.y = __builtin_amdgcn_exp2f(arg.y);
                f32x2 DDo = (ec + 1.f) * (eo + 1.f);
                f32x2 Rs;
                Rs.x = __builtin_amdgcn_rcpf(DDo.x); Rs.y = __builtin_amdgcn_rcpf(DDo.y);
                f32x2 h2 = (ec - 1.f) * Rs;
                half2v hp = __builtin_amdgcn_cvt_pkrtz(h2.x, h2.y);
                bh[2 * idx] = hp.x; bh[2 * idx + 1] = hp.y;
            }
        }

        // ---- pos_n^T = Whp*h^T + bhp (rows 0,1 -> q==0, regs 0,1) ----
        f32x4 ap;
        ap[0] = pb0; ap[1] = pb1; ap[2] = 0.f; ap[3] = 0.f;
        ap = MFMA(pht, bh, ap);

        // ---- gates_{n+1}^T = Wc_perm*h^T + bg2 (weights+bias from LDS) ----
        #pragma unroll
        for (int t8 = 0; t8 < 8; ++t8) {
            f32x4 a = BIA(t8);
            accg[t8] = MFMA(WHT(t8), bh, a);
        }

        // ---- cumsum + coalesced float2 store (lanes 0..15) ----
        if (q == 0) {
            run0 += ap[0]; run1 += ap[1];
            float2 w2; w2.x = run0; w2.y = run1;
            *(float2*)(out + 2 * ((size_t)n * Bn + base + col)) = w2;
        }
    }

    // ---- final hidden state from the f16 fragment (error ~2.4e-4) ----
    {
        float* p = out + (size_t)T * Bn * 2 + (size_t)(base + col) * 32 + 8 * q;
        float4 v0, v1;
        v0.x = (float)bh[0]; v0.y = (float)bh[1]; v0.z = (float)bh[2]; v0.w = (float)bh[3];
        v1.x = (float)bh[4]; v1.y = (float)bh[5]; v1.z = (float)bh[6]; v1.w = (float)bh[7];
        *(float4*)(p)     = v0;
        *(float4*)(p + 4) = v1;
    }
    #undef WHT
    #undef BIA
}

extern "C" void kernel_launch(void* const* d_in, const int* in_sizes, int n_in,
                              void* d_out, int out_size, void* d_ws, size_t ws_size,
                              hipStream_t stream) {
    const float* last_pos_rel = (const float*)d_in[0];
    const float* hidden_state = (const float*)d_in[1];
    const float* start_pos    = (const float*)d_in[2];
    const float* W_se         = (const float*)d_in[3];
    const float* b_se         = (const float*)d_in[4];
    const float* W_ih         = (const float*)d_in[5];
    const float* b_ih         = (const float*)d_in[6];
    const float* W_hh         = (const float*)d_in[7];
    const float* b_hh         = (const float*)d_in[8];
    const float* W_hp         = (const float*)d_in[9];
    const float* b_hp         = (const float*)d_in[10];
    const int*   seq_len      = (const int*)d_in[11];

    float* out = (float*)d_out;
    float* ws  = (float*)d_ws;

    const int Bn = in_sizes[0] / 2;

    hipLaunchKernelGGL(precompute_kernel, dim3(1), dim3(128), 0, stream,
                       W_se, b_se, W_ih, b_ih, W_hh, b_hh, W_hp, b_hp, ws);

    const int ntiles = (Bn + 15) / 16;
    const int nblk   = (ntiles + 3) / 4;
    hipLaunchKernelGGL(lstm_kernel, dim3(nblk), dim3(256), 0, stream,
                       last_pos_rel, hidden_state, start_pos, b_hp,
                       ws, seq_len, out, Bn);
}

// Round 15
// 197.521 us; speedup vs baseline: 1.2211x; 1.0535x over previous
//
#include <hip/hip_runtime.h>

typedef _Float16 half8  __attribute__((ext_vector_type(8)));
typedef __fp16   half2v __attribute__((ext_vector_type(2)));   // cvt_pkrtz return type
typedef float    f32x4  __attribute__((ext_vector_type(4)));
typedef float    f32x2  __attribute__((ext_vector_type(2)));

#define L2E 1.44269504088896340736f
#define MFMA(a, b, c) __builtin_amdgcn_mfma_f32_16x16x32_f16((a), (b), (c), 0, 0, 0)

// Row-permuted + pre-scaled weights: D-fragment of gates^T = Wc·h^T lands
// i,f,g,o for (agent=col, j=8q+i) in-lane; activation output is directly the
// next step's B-fragment. slot s: gi=s>>5, hf=(s>>4)&1, q=(s>>2)&3, r=s&3
//   -> orig gate row o = gi*32 + 8q + 4hf + r.
// ws layout (float offsets):
//   0    : Wcs [128][32]  permuted, scaled folded recurrent weights
//   8192 : W00s[128]      permuted, scaled lp0 rank-1 column
//   8320 : W01s[128]      permuted, scaled lp1 rank-1 column
//   8448 : bg2s[128]      permuted, scaled steady-state gate bias
//   8704 : phf [64][4]    per-lane prebuilt f16 pos-head A-fragment (u32 x4)
__global__ void precompute_kernel(const float* __restrict__ W_se,
                                  const float* __restrict__ b_se,
                                  const float* __restrict__ W_ih,
                                  const float* __restrict__ b_ih,
                                  const float* __restrict__ W_hh,
                                  const float* __restrict__ b_hh,
                                  const float* __restrict__ W_hp,
                                  const float* __restrict__ b_hp,
                                  float* __restrict__ ws) {
    int s = threadIdx.x;
    if (s >= 128) return;
    // pos-head fragment table (lanes 0..63)
    if (s < 64) {
        int colp = s & 15, qp = s >> 4;
        unsigned int* dst = (unsigned int*)ws + 8704 + s * 4;
        for (int pp = 0; pp < 4; ++pp) {
            float v0 = (colp < 2) ? W_hp[colp * 32 + 8 * qp + 2 * pp]     : 0.f;
            float v1 = (colp < 2) ? W_hp[colp * 32 + 8 * qp + 2 * pp + 1] : 0.f;
            half2v h2 = __builtin_amdgcn_cvt_pkrtz(v0, v1);
            dst[pp] = __builtin_bit_cast(unsigned int, h2);
        }
    }
    int gi = s >> 5, hf = (s >> 4) & 1, q = (s >> 2) & 3, r = s & 3;
    int o  = gi * 32 + 8 * q + 4 * hf + r;          // original gate row
    float w0 = 0.f, w1 = 0.f, bse = 0.f;
    for (int e = 0; e < 32; ++e) {
        float wi = W_ih[o * 32 + e];
        w0  += W_se[e * 2 + 0] * wi;
        w1  += W_se[e * 2 + 1] * wi;
        bse += b_se[e] * wi;
    }
    // i,f,o rows scaled by -log2e (sigmoid via exp2); g rows by 2*log2e (tanh)
    float sc = (gi == 2) ? 2.0f * L2E : -L2E;
    for (int k = 0; k < 32; ++k) {
        float whh = W_hh[o * 32 + k];
        ws[s * 32 + k] = sc * (whh + W_hp[k] * w0 + W_hp[32 + k] * w1);
    }
    float bg = b_ih[o] + b_hh[o] + bse;
    ws[8192 + s] = sc * w0;
    ws[8320 + s] = sc * w1;
    ws[8448 + s] = sc * (bg + b_hp[0] * w0 + b_hp[1] * w1);
}

// exact hi/lo f16 split of 8 floats
__device__ __forceinline__ void split8(const float* v, half8& hi, half8& lo) {
    #pragma unroll
    for (int p = 0; p < 4; ++p) {
        half2v hp = __builtin_amdgcn_cvt_pkrtz(v[2 * p], v[2 * p + 1]);
        hi[2 * p] = hp.x; hi[2 * p + 1] = hp.y;
        float l0 = v[2 * p]     - (float)hp.x;
        float l1 = v[2 * p + 1] - (float)hp.y;
        half2v lp2 = __builtin_amdgcn_cvt_pkrtz(l0, l1);
        lo[2 * p] = lp2.x; lo[2 * p + 1] = lp2.y;
    }
}

// Single tile per wave, 4 waves/block. Weight fragments in per-block LDS;
// per iteration ALL 8 volatile ds_reads are issued at the loop top into
// transient temps so their latency hides under the ~450-cycle activation
// phase (temps die within the iteration -> no persistent-register cost).
__global__ __launch_bounds__(256, 4) void lstm_kernel(
        const float* __restrict__ lp,    // last_pos_rel (B,2)
        const float* __restrict__ h0g,   // hidden_state (1,B,32)
        const float* __restrict__ sp,    // start_pos (B,2)
        const float* __restrict__ bhp,   // (2)
        const float* __restrict__ ws,
        const int*   __restrict__ seqp,
        float* __restrict__ out, int Bn) {
    __shared__ f32x4 wh_lds[8][64];      // [t8][lane] f16x8 fragments, 8 KB

    const int tid  = threadIdx.x;
    const int lane = tid & 63;
    const int col  = lane & 15;          // agent within tile
    const int q    = lane >> 4;
    int base = (blockIdx.x * 4 + (tid >> 6)) * 16;
    if (base + 16 > Bn) base = (Bn >= 16) ? (Bn - 16) : 0;   // clamp; no early return (barrier)
    const int T = seqp[0];

    const float* Wcs  = ws;
    const float* W00s = ws + 8192;
    const float* W01s = ws + 8320;
    const float* bg2q = ws + 8448 + 4 * q;   // per-lane bias base
    const float* phb  = ws + 8704;           // pos-head fragment table

    // ---- build the shared weight-fragment table (wave 0 only) ----
    if (tid < 64) {
        #pragma unroll
        for (int t8 = 0; t8 < 8; ++t8) {
            const float* p = Wcs + (size_t)(t8 * 16 + (tid & 15)) * 32 + 8 * (tid >> 4);
            half8 w;
            #pragma unroll
            for (int pp = 0; pp < 4; ++pp) {
                half2v h2 = __builtin_amdgcn_cvt_pkrtz(p[2 * pp], p[2 * pp + 1]);
                w[2 * pp] = h2.x; w[2 * pp + 1] = h2.y;
            }
            wh_lds[t8][tid] = __builtin_bit_cast(f32x4, w);
        }
    }
    __syncthreads();

    // volatile LDS read: one ds_read_b128, never hoisted to persistent regs
    #define WHT(t8) __builtin_bit_cast(half8, *(volatile const f32x4*)&wh_lds[(t8)][lane])

    // persistent pos-head fragment (4 regs) + bias scalars
    half8 pht = __builtin_bit_cast(half8, *(const f32x4*)(phb + lane * 4));
    const float pb0 = (q == 0) ? bhp[0] : 0.f;
    const float pb1 = (q == 0) ? bhp[1] : 0.f;

    // ---- step 0 via correction identity:
    //      gates_0 = wh*h0 + bg2 + W0 (x) (lp - (Whp*h0 + bhp)) ----
    f32x4 accg[8];
    {
        half8 b0h, b0l;                  // h0 fragment, exact hi/lo
        {
            float v[8];
            const float* p = h0g + (size_t)(base + col) * 32 + 8 * q;
            #pragma unroll
            for (int i = 0; i < 8; ++i) v[i] = p[i];
            split8(v, b0h, b0l);
        }
        f32x4 ap;
        ap[0] = pb0; ap[1] = pb1; ap[2] = 0.f; ap[3] = 0.f;
        ap = MFMA(pht, b0h, ap);
        ap = MFMA(pht, b0l, ap);
        half8 dh;                        // delta = lp - p~  (k=0,1 live on q==0)
        #pragma unroll
        for (int i = 0; i < 8; ++i) dh[i] = (_Float16)0.f;
        if (q == 0) {
            float d0 = lp[(size_t)(base + col) * 2 + 0] - ap[0];
            float d1 = lp[(size_t)(base + col) * 2 + 1] - ap[1];
            half2v x = __builtin_amdgcn_cvt_pkrtz(d0, d1);
            dh[0] = x.x; dh[1] = x.y;
        }
        #pragma unroll
        for (int t8 = 0; t8 < 8; ++t8) {
            f32x4 a = *(const f32x4*)(bg2q + t8 * 16);
            half8 w = WHT(t8);
            a = MFMA(w, b0h, a);
            a = MFMA(w, b0l, a);
            half8 ch;                    // rank-2 correction A-fragment
            #pragma unroll
            for (int i = 0; i < 8; ++i) ch[i] = (_Float16)0.f;
            if (q == 0) {
                half2v y = __builtin_amdgcn_cvt_pkrtz(W00s[t8 * 16 + col],
                                                      W01s[t8 * 16 + col]);
                ch[0] = y.x; ch[1] = y.y;
            }
            a = MFMA(ch, dh, a);
            accg[t8] = a;
        }
    }

    // per-lane recurrent state: agent=col, hidden j = 8q+i
    f32x2 c2[4];
    #pragma unroll
    for (int i = 0; i < 4; ++i) c2[i] = (f32x2)0.f;
    float run0 = 0.f, run1 = 0.f;
    if (q == 0) {
        run0 = sp[(size_t)(base + col) * 2 + 0];
        run1 = sp[(size_t)(base + col) * 2 + 1];
    }

    half8 bh;                            // h as f16 B-fragment (persists to epilogue)

    #pragma unroll 1
    for (int n = 0; n < T; ++n) {
        // ---- prefetch this step's weight fragments (8 x ds_read_b128);
        //      latency hides under the activation transcendentals below ----
        half8 w8[8];
        #pragma unroll
        for (int t8 = 0; t8 < 8; ++t8) w8[t8] = WHT(t8);

        // ---- activations: accg[2*gi+hf][r] -> bh (f16), c2 (f32) ----
        #pragma unroll
        for (int hf = 0; hf < 2; ++hf) {
            #pragma unroll
            for (int rp = 0; rp < 2; ++rp) {
                const int idx = 2 * hf + rp;
                f32x2 gI, gF, gG, gO;
                gI.x = accg[0 + hf][2 * rp]; gI.y = accg[0 + hf][2 * rp + 1];
                gF.x = accg[2 + hf][2 * rp]; gF.y = accg[2 + hf][2 * rp + 1];
                gG.x = accg[4 + hf][2 * rp]; gG.y = accg[4 + hf][2 * rp + 1];
                gO.x = accg[6 + hf][2 * rp]; gO.y = accg[6 + hf][2 * rp + 1];
                f32x2 ei, ef, eg, eo;
                ei.x = __builtin_amdgcn_exp2f(gI.x); ei.y = __builtin_amdgcn_exp2f(gI.y);
                ef.x = __builtin_amdgcn_exp2f(gF.x); ef.y = __builtin_amdgcn_exp2f(gF.y);
                eg.x = __builtin_amdgcn_exp2f(gG.x); eg.y = __builtin_amdgcn_exp2f(gG.y);
                eo.x = __builtin_amdgcn_exp2f(gO.x); eo.y = __builtin_amdgcn_exp2f(gO.y);
                f32x2 Df = ef + 1.f;
                f32x2 P  = (ei + 1.f) * (eg + 1.f);
                f32x2 PD = P * Df;
                f32x2 R;
                R.x = __builtin_amdgcn_rcpf(PD.x); R.y = __builtin_amdgcn_rcpf(PD.y);
                f32x2 cn = ((eg - 1.f) * Df + c2[idx] * P) * R;
                c2[idx] = cn;
                f32x2 arg = cn * (2.f * L2E);
                f32x2 ec;
                ec.x = __builtin_amdgcn_exp2f(arg.x); ec.y = __builtin_amdgcn_exp2f(arg.y);
                f32x2 DDo = (ec + 1.f) * (eo + 1.f);
                f32x2 Rs;
                Rs.x = __builtin_amdgcn_rcpf(DDo.x); Rs.y = __builtin_amdgcn_rcpf(DDo.y);
                f32x2 h2 = (ec - 1.f) * Rs;
                half2v hp = __builtin_amdgcn_cvt_pkrtz(h2.x, h2.y);
                bh[2 * idx] = hp.x; bh[2 * idx + 1] = hp.y;
            }
        }

        // ---- pos_n^T = Whp*h^T + bhp (rows 0,1 -> q==0, regs 0,1) ----
        f32x4 ap;
        ap[0] = pb0; ap[1] = pb1; ap[2] = 0.f; ap[3] = 0.f;
        ap = MFMA(pht, bh, ap);

        // ---- gates_{n+1}^T = Wc_perm*h^T + bg2 (weights already in regs) ----
        #pragma unroll
        for (int t8 = 0; t8 < 8; ++t8) {
            f32x4 a = *(const f32x4*)(bg2q + t8 * 16);   // L1-hot, 16 B
            accg[t8] = MFMA(w8[t8], bh, a);
        }

        // ---- cumsum + coalesced float2 store (lanes 0..15) ----
        if (q == 0) {
            run0 += ap[0]; run1 += ap[1];
            float2 w2; w2.x = run0; w2.y = run1;
            *(float2*)(out + 2 * ((size_t)n * Bn + base + col)) = w2;
        }
    }

    // ---- final hidden state from the f16 fragment (error ~2.4e-4) ----
    {
        float* p = out + (size_t)T * Bn * 2 + (size_t)(base + col) * 32 + 8 * q;
        float4 v0, v1;
        v0.x = (float)bh[0]; v0.y = (float)bh[1]; v0.z = (float)bh[2]; v0.w = (float)bh[3];
        v1.x = (float)bh[4]; v1.y = (float)bh[5]; v1.z = (float)bh[6]; v1.w = (float)bh[7];
        *(float4*)(p)     = v0;
        *(float4*)(p + 4) = v1;
    }
    #undef WHT
}

extern "C" void kernel_launch(void* const* d_in, const int* in_sizes, int n_in,
                              void* d_out, int out_size, void* d_ws, size_t ws_size,
                              hipStream_t stream) {
    const float* last_pos_rel = (const float*)d_in[0];
    const float* hidden_state = (const float*)d_in[1];
    const float* start_pos    = (const float*)d_in[2];
    const float* W_se         = (const float*)d_in[3];
    const float* b_se         = (const float*)d_in[4];
    const float* W_ih         = (const float*)d_in[5];
    const float* b_ih         = (const float*)d_in[6];
    const float* W_hh         = (const float*)d_in[7];
    const float* b_hh         = (const float*)d_in[8];
    const float* W_hp         = (const float*)d_in[9];
    const float* b_hp         = (const float*)d_in[10];
    const int*   seq_len      = (const int*)d_in[11];

    float* out = (float*)d_out;
    float* ws  = (float*)d_ws;

    const int Bn = in_sizes[0] / 2;

    hipLaunchKernelGGL(precompute_kernel, dim3(1), dim3(128), 0, stream,
                       W_se, b_se, W_ih, b_ih, W_hh, b_hh, W_hp, b_hp, ws);

    const int ntiles = (Bn + 15) / 16;
    const int nblk   = (ntiles + 3) / 4;
    hipLaunchKernelGGL(lstm_kernel, dim3(nblk), dim3(256), 0, stream,
                       last_pos_rel, hidden_state, start_pos, b_hp,
                       ws, seq_len, out, Bn);
}